// Round 11
// baseline (102.076 us; speedup 1.0000x reference)
//
#include <hip/hip_runtime.h>
#include <hip/hip_bf16.h>

typedef float f32x4 __attribute__((ext_vector_type(4)));
typedef short s16x8 __attribute__((ext_vector_type(8)));

#define D_DIM 4096
#define NT 24            // 16-wide col tiles (global)
#define BM 128           // rows per block
#define NBODY 32         // bodies per block, BK=32
// LDS: B[2][12288] @ 0, A[2][8192] @ 24576 -> 40960 B
#define BOFF 0
#define AOFF 24576
// ws byte offsets
#define SINW_OFF 3145728u                 // sinws[4][8192] f32 = 128 KiB
#define PART_OFF 3276800u                 // part[4][8192][384] f16 = 24 MiB

__device__ __forceinline__ unsigned short f2bf(float f) {
    unsigned u = __float_as_uint(f);
    u += 0x7fffu + ((u >> 16) & 1u);   // RNE
    return (unsigned short)(u >> 16);
}

__device__ __forceinline__ void gload16(const void* g, void* l) {
    __builtin_amdgcn_global_load_lds(
        (const __attribute__((address_space(1))) unsigned int*)g,
        (__attribute__((address_space(3))) unsigned int*)l, 16, 0, 0);
}

__global__ __launch_bounds__(64) void reg_init_kernel(const float* __restrict__ C,
                                                      const float* __restrict__ Csin,
                                                      float* __restrict__ reg_out) {
    if (threadIdx.x == 0)
        reg_out[0] = 0.05f * (fabsf(C[0]) + fabsf(C[1]) + fabsf(C[2]) + fabsf(Csin[0]));
}

// Build W [4096 x 384] bf16, MFMA B-fragment-packed, slab-contiguous:
// chunk = (k>>5)*NT + (n>>4); lane = ((k&31)>>3)*16 | (n&15); j = k&7.
// Slab s (32 k's) = bytes [s*24576, (s+1)*24576), 24 chunks of 1 KB.
__global__ __launch_bounds__(64) void build_w_kernel(const float* __restrict__ U1,
                                                     const float* __restrict__ U2,
                                                     const float* __restrict__ U3,
                                                     unsigned short* __restrict__ W,
                                                     float* __restrict__ reg_out) {
    const int ks = blockIdx.x / NT;
    const int ct = blockIdx.x % NT;
    const int l  = threadIdx.x;
    const int n  = ct * 16 + (l & 15);
    const int kb = ks * 32 + ((l >> 4) << 3);

    const float* src;
    float scale;
    if (n < 64)       { src = U1 + n;                  scale = 0.01f / 262144.f; }
    else if (n < 128) { src = U2 + (n - 64);           scale = 0.01f / 524288.f; }
    else if (n < 192) { src = U2 + 262144 + (n - 128); scale = 0.01f / 524288.f; }
    else if (n < 256) { src = U3 + (n - 192);          scale = 0.01f / 786432.f; }
    else if (n < 320) { src = U3 + 262144 + (n - 256); scale = 0.01f / 786432.f; }
    else              { src = U3 + 524288 + (n - 320); scale = 0.01f / 786432.f; }

    unsigned short h[8];
    float sabs = 0.f;
#pragma unroll
    for (int j = 0; j < 8; ++j) {
        float u = src[(size_t)(kb + j) * 64];
        sabs += fabsf(u);
        h[j] = f2bf(u);
    }
    uint4 pk;
    pk.x = (unsigned)h[0] | ((unsigned)h[1] << 16);
    pk.y = (unsigned)h[2] | ((unsigned)h[3] << 16);
    pk.z = (unsigned)h[4] | ((unsigned)h[5] << 16);
    pk.w = (unsigned)h[6] | ((unsigned)h[7] << 16);
    *(uint4*)(W + ((size_t)blockIdx.x * 64 + l) * 8) = pk;

    sabs *= scale;
#pragma unroll
    for (int off = 32; off >= 1; off >>= 1)
        sabs += __shfl_xor(sabs, off, 64);
    if (l == 0) atomicAdd(reg_out, sabs);
}

// grid 512 = rb(64) x cs(2) x kh(4); blockIdx = rb*8 + cs*4 + kh so
// XCD = blockIdx%8 = (cs,kh): per-XCD W slice = 192x1024x2B = 384 KB (L2-hot).
// Block: 512 thr = 8 waves (2 rg x 4 cg), 128 rows x 192 cols x 1024 K,
// 32 bodies BK=32. TWO blocks/CU = two independent barrier groups (m97/m114:
// cross-group co-scheduling hides each group's phase bubbles).
// Per body: issue B(d+1) via gload_lds (12 x 1KB, zero VGPR), load X(d+2) to
// regs, stage A(d+1) (sin cs==0 + cvt + 1 ds_write_b128/thread), ds_read
// 4 A + 3 B frags, lgkm-only MFMA wall, 12 MFMA, counted vmcnt(2) + raw
// s_barrier (X loads cross barriers; never vmcnt(0) in loop).
__global__ __launch_bounds__(512, 4) void poly_main_kernel(const float* __restrict__ X,
                                                           const unsigned short* __restrict__ W,
                                                           _Float16* __restrict__ part,
                                                           float* __restrict__ sinws) {
    __shared__ __align__(16) char pool[40960];

    const int t    = threadIdx.x;
    const int lane = t & 63;
    const int wv   = t >> 6;          // 0..7
    const int rg   = wv >> 2;         // 0..1
    const int cg   = wv & 3;          // 0..3
    const int ct0  = cg * 3;          // local col-tile base (strip-relative)
    const int rb   = blockIdx.x >> 3;
    const int cs   = (blockIdx.x >> 2) & 1;
    const int kh   = blockIdx.x & 3;
    const int row0 = rb * BM;
    const bool doSin = (cs == 0);

    // A staging: thread -> (row sr, kslot q: 8 k's)
    const int sr = t >> 2;                // 0..127
    const int q  = t & 3;                 // kslot
    const float* xp = X + (size_t)(row0 + sr) * D_DIM + kh * 1024 + q * 8;
    const int awfrag = (sr >> 4) * 1024 + (((q << 4) | (sr & 15)) << 4);

    // B chunk assignment: waves 0-3 issue 2 chunks, waves 4-7 issue 1
    const int nB  = (wv < 4) ? 2 : 1;
    const int ch0 = (wv < 4) ? (wv * 2) : (4 + wv);
    const int slab0 = kh * 32;
    // element offsets into W (ushort): slab*12288 + cs*6144 + ch*512 + lane*8
    const unsigned short* wbase = W + (size_t)slab0 * 12288 + cs * 6144
                                    + ch0 * 512 + lane * 8;

    f32x4 acc[4][3];
#pragma unroll
    for (int r = 0; r < 4; ++r)
#pragma unroll
        for (int c = 0; c < 3; ++c) acc[r][c] = (f32x4){0.f, 0.f, 0.f, 0.f};
    float sinacc = 0.f;
    f32x4 xn0, xn1;

#define STAGE(bufl, XA, XB)                                                     \
    {                                                                           \
        if (doSin)                                                              \
            sinacc += __sinf(XA.x) + __sinf(XA.y) + __sinf(XA.z) + __sinf(XA.w) \
                    + __sinf(XB.x) + __sinf(XB.y) + __sinf(XB.z) + __sinf(XB.w);\
        uint4 h_;                                                               \
        h_.x = (unsigned)f2bf(XA.x) | ((unsigned)f2bf(XA.y) << 16);             \
        h_.y = (unsigned)f2bf(XA.z) | ((unsigned)f2bf(XA.w) << 16);             \
        h_.z = (unsigned)f2bf(XB.x) | ((unsigned)f2bf(XB.y) << 16);             \
        h_.w = (unsigned)f2bf(XB.z) | ((unsigned)f2bf(XB.w) << 16);             \
        *(uint4*)(pool + AOFF + (bufl) * 8192 + awfrag) = h_;                   \
    }

    // ---- prologue: B(0) -> buf0; X(0) staged; X(1) in flight ----
    gload16(wbase, pool + BOFF + ch0 * 1024);
    if (nB == 2) gload16(wbase + 512, pool + BOFF + (ch0 + 1) * 1024);
    {
        f32x4 x00 = *(const f32x4*)xp;
        f32x4 x01 = *(const f32x4*)(xp + 4);
        STAGE(0, x00, x01);
        xn0 = *(const f32x4*)(xp + 32);
        xn1 = *(const f32x4*)(xp + 36);
    }
    asm volatile("s_waitcnt lgkmcnt(0)" ::: "memory");
    asm volatile("s_waitcnt vmcnt(2)" ::: "memory");   // B(0) landed; X(1) flying
    __builtin_amdgcn_s_barrier();
    __builtin_amdgcn_sched_barrier(0);

#define BODY(d_, CUR, NXT)                                                      \
    {                                                                           \
        const int d__ = (d_);                                                   \
        if (d__ + 1 < NBODY) {                                                  \
            const unsigned short* g_ = wbase + (size_t)(d__ + 1) * 12288;       \
            gload16(g_, pool + BOFF + (NXT) * 12288 + ch0 * 1024);              \
            if (nB == 2)                                                        \
                gload16(g_ + 512, pool + BOFF + (NXT) * 12288 + (ch0 + 1) * 1024);\
        }                                                                       \
        int sl_ = d__ + 2; if (sl_ > NBODY - 1) sl_ = NBODY - 1;                \
        f32x4 xf0_ = *(const f32x4*)(xp + (size_t)sl_ * 32);                    \
        f32x4 xf1_ = *(const f32x4*)(xp + (size_t)sl_ * 32 + 4);                \
        if (d__ + 1 < NBODY) { STAGE(NXT, xn0, xn1); }                          \
        xn0 = xf0_; xn1 = xf1_;                                                 \
        const char* ab_ = pool + AOFF + (CUR) * 8192;                           \
        const char* bb_ = pool + BOFF + (CUR) * 12288;                          \
        s16x8 af0_ = *(const s16x8*)(ab_ + (rg * 4 + 0) * 1024 + lane * 16);    \
        s16x8 af1_ = *(const s16x8*)(ab_ + (rg * 4 + 1) * 1024 + lane * 16);    \
        s16x8 af2_ = *(const s16x8*)(ab_ + (rg * 4 + 2) * 1024 + lane * 16);    \
        s16x8 af3_ = *(const s16x8*)(ab_ + (rg * 4 + 3) * 1024 + lane * 16);    \
        s16x8 bf0_ = *(const s16x8*)(bb_ + (ct0 + 0) * 1024 + lane * 16);       \
        s16x8 bf1_ = *(const s16x8*)(bb_ + (ct0 + 1) * 1024 + lane * 16);       \
        s16x8 bf2_ = *(const s16x8*)(bb_ + (ct0 + 2) * 1024 + lane * 16);       \
        asm volatile("s_waitcnt lgkmcnt(0)" ::: "memory");                      \
        __builtin_amdgcn_sched_barrier(0);                                      \
        __builtin_amdgcn_s_setprio(1);                                          \
        acc[0][0] = __builtin_amdgcn_mfma_f32_16x16x32_bf16(af0_, bf0_, acc[0][0], 0, 0, 0); \
        acc[0][1] = __builtin_amdgcn_mfma_f32_16x16x32_bf16(af0_, bf1_, acc[0][1], 0, 0, 0); \
        acc[0][2] = __builtin_amdgcn_mfma_f32_16x16x32_bf16(af0_, bf2_, acc[0][2], 0, 0, 0); \
        acc[1][0] = __builtin_amdgcn_mfma_f32_16x16x32_bf16(af1_, bf0_, acc[1][0], 0, 0, 0); \
        acc[1][1] = __builtin_amdgcn_mfma_f32_16x16x32_bf16(af1_, bf1_, acc[1][1], 0, 0, 0); \
        acc[1][2] = __builtin_amdgcn_mfma_f32_16x16x32_bf16(af1_, bf2_, acc[1][2], 0, 0, 0); \
        acc[2][0] = __builtin_amdgcn_mfma_f32_16x16x32_bf16(af2_, bf0_, acc[2][0], 0, 0, 0); \
        acc[2][1] = __builtin_amdgcn_mfma_f32_16x16x32_bf16(af2_, bf1_, acc[2][1], 0, 0, 0); \
        acc[2][2] = __builtin_amdgcn_mfma_f32_16x16x32_bf16(af2_, bf2_, acc[2][2], 0, 0, 0); \
        acc[3][0] = __builtin_amdgcn_mfma_f32_16x16x32_bf16(af3_, bf0_, acc[3][0], 0, 0, 0); \
        acc[3][1] = __builtin_amdgcn_mfma_f32_16x16x32_bf16(af3_, bf1_, acc[3][1], 0, 0, 0); \
        acc[3][2] = __builtin_amdgcn_mfma_f32_16x16x32_bf16(af3_, bf2_, acc[3][2], 0, 0, 0); \
        __builtin_amdgcn_s_setprio(0);                                          \
        asm volatile("s_waitcnt vmcnt(2)" ::: "memory");                        \
        __builtin_amdgcn_s_barrier();                                           \
        __builtin_amdgcn_sched_barrier(0);                                      \
    }

    for (int d = 0; d < NBODY; d += 2) {
        BODY(d, 0, 1);
        BODY(d + 1, 1, 0);
    }
#undef BODY
#undef STAGE

    // ---- epilogue: f16 partial write + sin partial (no LDS, no syncs) ----
    _Float16* pb = part + (size_t)kh * 8192 * 384;
    const int lr4 = (lane >> 4) << 2;
    const int lc  = lane & 15;
#pragma unroll
    for (int rf = 0; rf < 4; ++rf)
#pragma unroll
        for (int c = 0; c < 3; ++c) {
            const int col = cs * 192 + (ct0 + c) * 16 + lc;
#pragma unroll
            for (int i = 0; i < 4; ++i) {
                const int rl = rg * 64 + rf * 16 + lr4 + i;
                pb[(size_t)(row0 + rl) * 384 + col] = (_Float16)acc[rf][c][i];
            }
        }

    if (doSin) {
        sinacc += __shfl_xor(sinacc, 1);
        sinacc += __shfl_xor(sinacc, 2);
        if ((t & 3) == 0)
            sinws[(size_t)kh * 8192 + row0 + sr] = sinacc;
    }
}

// combine: sum 4 K-quarter partials, nonlinear terms + sin + beta -> out.
__global__ __launch_bounds__(512) void combine_kernel(const _Float16* __restrict__ part,
                                                      const float* __restrict__ sinws,
                                                      const float* __restrict__ C,
                                                      const float* __restrict__ beta,
                                                      const float* __restrict__ Csin,
                                                      float* __restrict__ out) {
    const int t   = threadIdx.x;
    const int row = blockIdx.x * 32 + (t >> 4);
    const int cc  = t & 15;
    const size_t rbase = (size_t)row * 384;

    float t1 = 0.f, t2 = 0.f, t3 = 0.f;
#pragma unroll
    for (int j = 0; j < 4; ++j) {
        const int c = j * 16 + cc;
        float a1 = 0.f, a2 = 0.f, b2 = 0.f, a3 = 0.f, b3 = 0.f, c3 = 0.f;
#pragma unroll
        for (int qq = 0; qq < 4; ++qq) {
            const _Float16* p = part + (size_t)qq * 8192 * 384 + rbase;
            a1 += (float)p[c];
            a2 += (float)p[64 + c];
            b2 += (float)p[128 + c];
            a3 += (float)p[192 + c];
            b3 += (float)p[256 + c];
            c3 += (float)p[320 + c];
        }
        t1 += a1;
        t2 += a2 * b2;
        t3 += a3 * b3 * c3;
    }
#pragma unroll
    for (int off = 1; off < 16; off <<= 1) {
        t1 += __shfl_xor(t1, off, 16);
        t2 += __shfl_xor(t2, off, 16);
        t3 += __shfl_xor(t3, off, 16);
    }
    if (cc == 0) {
        const float s = sinws[row] + sinws[8192 + row]
                      + sinws[2 * 8192 + row] + sinws[3 * 8192 + row];
        out[row] = beta[0] + C[0] * t1 + C[1] * t2 + C[2] * t3 + Csin[0] * s;
    }
}

extern "C" void kernel_launch(void* const* d_in, const int* in_sizes, int n_in,
                              void* d_out, int out_size, void* d_ws, size_t ws_size,
                              hipStream_t stream) {
    const float* X   = (const float*)d_in[0];
    const float* U1  = (const float*)d_in[1];
    const float* U2  = (const float*)d_in[2];
    const float* U3  = (const float*)d_in[3];
    const float* Cc  = (const float*)d_in[4];
    const float* bet = (const float*)d_in[5];
    const float* Cs  = (const float*)d_in[6];
    float* out = (float*)d_out;

    unsigned short* W = (unsigned short*)d_ws;                  // 3 MiB, frag-packed
    float* sinws = (float*)((char*)d_ws + SINW_OFF);            // 128 KiB
    _Float16* part = (_Float16*)((char*)d_ws + PART_OFF);       // 24 MiB

    reg_init_kernel<<<1, 64, 0, stream>>>(Cc, Cs, out + 8192);
    build_w_kernel<<<128 * NT, 64, 0, stream>>>(U1, U2, U3, W, out + 8192);
    poly_main_kernel<<<512, 512, 0, stream>>>(X, W, part, sinws);
    combine_kernel<<<256, 512, 0, stream>>>(part, sinws, Cc, bet, Cs, out);
}